// Round 12
// baseline (281.548 us; speedup 1.0000x reference)
//
#include <hip/hip_runtime.h>

// ---------------------------------------------------------------------------
// GCN 2-layer, CSR-gather. R23 (on R22 = 269.4us):
//  - Budget audit: top-5 is agg64f x5 every round -> agg16f hidden at ~50-65us
//    (bounded only by cutoff). Its 16-lane groups have 4-way degree
//    divergence, vector ep loads, 32B/gather.
//  - k_agg16f -> k_agg16w: WAVE per node. lane=(edge-slot es, feature f):
//    one gather = 4 edges (64 lanes x 2B); ep via s_load (readfirstlane node,
//    agg64's proven SGPR trick); slot partials combined shfl_xor(16/32);
//    fused +b2 log_softmax kept. 1-deep ep prefetch.
//  - agg64f/gemm1/p1/pscan/p2 unchanged (R22 measured forms).
// ---------------------------------------------------------------------------

#define BSHIFT 7
#define BNODES 128
#define NBUK_MAX 1024
#define CSTR 16
#define CAP 3072
#define CHUNK 8192
#define EPB 8
#define P1_TB 1024

typedef unsigned short ushort_t;
typedef unsigned int uint_t;
typedef unsigned short us4 __attribute__((ext_vector_type(4)));

__device__ inline ushort_t f2bf(float f) {   // round-to-nearest-even
    uint_t u = __float_as_uint(f);
    return (ushort_t)((u + 0x7FFF + ((u >> 16) & 1)) >> 16);
}
__device__ inline float bf2f(ushort_t b) {
    return __uint_as_float(((uint_t)b) << 16);
}

// init strided cursors to their segment bases
__global__ __launch_bounds__(1024) void k_binit(int* __restrict__ bcur, int nbuk) {
    int t = threadIdx.x;
    if (t < nbuk) bcur[t * CSTR] = t * CAP;
}

// Pass 1: block-aggregated bucket append (R18: 1024 threads, CHUNK 8192).
__global__ __launch_bounds__(1024) void k_p1(const int* __restrict__ src,
                                             const int* __restrict__ dst,
                                             const float* __restrict__ ew,
                                             int* __restrict__ bcur,
                                             int2* __restrict__ tmp, int E, int nbuk) {
    __shared__ int lcnt[NBUK_MAX];
    __shared__ int lbase[NBUK_MAX];
    const int t = threadIdx.x;
    const int base = blockIdx.x * CHUNK;
    for (int j = t; j < nbuk; j += P1_TB) lcnt[j] = 0;
    __syncthreads();
    int d_r[EPB];
#pragma unroll
    for (int k = 0; k < EPB; ++k) {
        int e = base + k * P1_TB + t;
        int d = (e < E) ? dst[e] : -1;
        d_r[k] = d;
        if (d >= 0) atomicAdd(&lcnt[d >> BSHIFT], 1);
    }
    __syncthreads();
    for (int j = t; j < nbuk; j += P1_TB) {
        int c = lcnt[j];
        lbase[j] = c ? atomicAdd(&bcur[j * CSTR], c) : 0;
        lcnt[j] = 0;
    }
    __syncthreads();
#pragma unroll
    for (int k = 0; k < EPB; ++k) {
        int d = d_r[k];
        if (d < 0) continue;
        int e = base + k * P1_TB + t;
        int b = d >> BSHIFT;
        int p = lbase[b] + atomicAdd(&lcnt[b], 1);
        if (p >= nbuk * CAP) continue;
        int2 pk;
        pk.x = src[e] | ((d & (BNODES - 1)) << 17);
        pk.y = __float_as_int(ew[e]);
        tmp[p] = pk;
    }
}

// Scan final bucket counts -> dense boff[nbuk+1].
__global__ __launch_bounds__(1024) void k_pscan(const int* __restrict__ bcur,
                                                int* __restrict__ boff, int nbuk) {
    __shared__ int lds[1024];
    const int t = threadIdx.x;
    int v = (t < nbuk) ? (bcur[t * CSTR] - t * CAP) : 0;
    lds[t] = v;
    __syncthreads();
    for (int off = 1; off < 1024; off <<= 1) {
        int u = (t >= off) ? lds[t - off] : 0;
        __syncthreads();
        lds[t] += u;
        __syncthreads();
    }
    if (t < nbuk) boff[t] = lds[t] - v;
    if (t == nbuk - 1) boff[nbuk] = lds[t];
}

// Pass 2: per-bucket finalize -> dense CSR epack {src, ew}, rowptr, dinv.
__global__ __launch_bounds__(256) void k_p2(const int2* __restrict__ tmp,
                                            const int* __restrict__ bcur,
                                            const int* __restrict__ boff,
                                            int* __restrict__ rowptr,
                                            int2* __restrict__ epack,
                                            float* __restrict__ dinv,
                                            int n, int nbuk) {
    __shared__ int cnt[BNODES];
    __shared__ int pos[BNODES];
    __shared__ float degf[BNODES];
    const int b = blockIdx.x, t = threadIdx.x;
    const int node0 = b << BSHIFT;
    if (t < BNODES) { cnt[t] = 0; degf[t] = 0.f; }
    __syncthreads();
    const int lo_t = b * CAP, hi_t = bcur[b * CSTR];
    const int outb = boff[b];
    for (int i = lo_t + t; i < hi_t; i += 256) {
        int2 pk = tmp[i];
        int dlo = (pk.x >> 17) & (BNODES - 1);
        atomicAdd(&cnt[dlo], 1);
        atomicAdd(&degf[dlo], __int_as_float(pk.y));
    }
    __syncthreads();
    int own = (t < BNODES) ? cnt[t] : 0;
    if (t < BNODES) pos[t] = own;
    __syncthreads();
    for (int off = 1; off < BNODES; off <<= 1) {
        int u = (t < BNODES && t >= off) ? pos[t - off] : 0;
        __syncthreads();
        if (t < BNODES) pos[t] += u;
        __syncthreads();
    }
    if (t < BNODES) {
        int excl = pos[t] - own;
        int node = node0 + t;
        if (node < n) {
            rowptr[node] = outb + excl;
            dinv[node] = rsqrtf(1.0f + degf[t]);
        }
        pos[t] = excl;
    }
    if (b == nbuk - 1 && t == 0) rowptr[n] = outb + (hi_t - lo_t);
    __syncthreads();
    for (int i = lo_t + t; i < hi_t; i += 256) {
        int2 pk = tmp[i];
        int dlo = (pk.x >> 17) & (BNODES - 1);
        int p = outb + atomicAdd(&pos[dlo], 1);
        int2 o;
        o.x = pk.x & 0x1FFFF;
        o.y = pk.y;
        epack[p] = o;
    }
}

// h1s[n][64] (bf16) = (x[n][128] @ W[128][64]) * dinv[node]
// 64-node block; thread = (ng, fg) owns nodes {ng+16j} x feats {4fg..4fg+3}.
// K in FOUR 32-quarters; Ws 8KB + xs[64][36] 9KB = 17KB -> 8 blocks/CU.
__global__ __launch_bounds__(256) void k_gemm1(const float* __restrict__ x,
                                               const float* __restrict__ W,
                                               const float* __restrict__ dinv,
                                               ushort_t* __restrict__ h, int n) {
    __shared__ float Ws[32 * 64];    // 8 KB  current quarter's [kk][f]
    __shared__ float xs[64][36];     // 9 KB  quarter-K tile, +4 pad
    const int t = threadIdx.x;
    const int node0 = blockIdx.x * 64;
    const int fg = t & 15;           // feature quad: f = 4fg..4fg+3
    const int ng = t >> 4;           // 0..15; this thread's nodes: ng + 16j
    float4 acc[4];
#pragma unroll
    for (int j = 0; j < 4; ++j) acc[j] = make_float4(0.f, 0.f, 0.f, 0.f);
    const float4* Ws4 = (const float4*)Ws;   // Ws4[kk*16 + fg]
    for (int quar = 0; quar < 4; ++quar) {
        __syncthreads();             // LDS reuse guard
        for (int i = t; i < 32 * 64; i += 256) Ws[i] = W[quar * 2048 + i];
        for (int i = t; i < 64 * 8; i += 256) {
            int nn = i >> 3, q = i & 7;
            int node = node0 + nn;
            float4 v = (node < n) ? ((const float4*)x)[(size_t)node * 32 + quar * 8 + q]
                                  : make_float4(0.f, 0.f, 0.f, 0.f);
            *(float4*)&xs[nn][q * 4] = v;
        }
        __syncthreads();
#pragma unroll
        for (int kb = 0; kb < 8; ++kb) {
            float4 xv[4];
#pragma unroll
            for (int j = 0; j < 4; ++j)
                xv[j] = *(const float4*)&xs[ng + 16 * j][kb * 4];
            float4 w0 = Ws4[(kb * 4 + 0) * 16 + fg];
            float4 w1 = Ws4[(kb * 4 + 1) * 16 + fg];
            float4 w2 = Ws4[(kb * 4 + 2) * 16 + fg];
            float4 w3 = Ws4[(kb * 4 + 3) * 16 + fg];
#pragma unroll
            for (int j = 0; j < 4; ++j) {
                acc[j].x = fmaf(xv[j].x, w0.x, acc[j].x);
                acc[j].y = fmaf(xv[j].x, w0.y, acc[j].y);
                acc[j].z = fmaf(xv[j].x, w0.z, acc[j].z);
                acc[j].w = fmaf(xv[j].x, w0.w, acc[j].w);
                acc[j].x = fmaf(xv[j].y, w1.x, acc[j].x);
                acc[j].y = fmaf(xv[j].y, w1.y, acc[j].y);
                acc[j].z = fmaf(xv[j].y, w1.z, acc[j].z);
                acc[j].w = fmaf(xv[j].y, w1.w, acc[j].w);
                acc[j].x = fmaf(xv[j].z, w2.x, acc[j].x);
                acc[j].y = fmaf(xv[j].z, w2.y, acc[j].y);
                acc[j].z = fmaf(xv[j].z, w2.z, acc[j].z);
                acc[j].w = fmaf(xv[j].z, w2.w, acc[j].w);
                acc[j].x = fmaf(xv[j].w, w3.x, acc[j].x);
                acc[j].y = fmaf(xv[j].w, w3.y, acc[j].y);
                acc[j].z = fmaf(xv[j].w, w3.z, acc[j].z);
                acc[j].w = fmaf(xv[j].w, w3.w, acc[j].w);
            }
        }
    }
#pragma unroll
    for (int j = 0; j < 4; ++j) {
        int node = node0 + ng + 16 * j;
        if (node < n) {
            float di = dinv[node];
            us4 pk;
            pk.x = f2bf(acc[j].x * di);
            pk.y = f2bf(acc[j].y * di);
            pk.z = f2bf(acc[j].z * di);
            pk.w = f2bf(acc[j].w * di);
            *(us4*)(h + (size_t)node * 64 + fg * 4) = pk;   // one 8B store
        }
    }
}

// Gather-aggregate F=64 with FUSED layer-2 gemm. One wave per node, lane =
// feature. R22 form: 1024-thread blocks, 2-deep pipeline, LDS epilogue.
__global__ __launch_bounds__(1024) void k_agg64f(const ushort_t* __restrict__ h,
                                                 const int* __restrict__ rowptr,
                                                 const int2* __restrict__ ep,
                                                 const float* __restrict__ dinv,
                                                 const float* __restrict__ W2,
                                                 const float* __restrict__ b1,
                                                 ushort_t* __restrict__ h2, int n) {
    __shared__ float W2s[64 * 17];   // padded [k][f]: W2s[k*17+f], 4.25 KB
    __shared__ float avs[16][64];    // per-wave relu'd agg row, 4 KB
    const int t = threadIdx.x;
    if (t < 64 * 16) {
        int k = t >> 4, f = t & 15;
        W2s[k * 17 + f] = W2[t];
    }
    __syncthreads();                 // before any divergent return
    const int node = __builtin_amdgcn_readfirstlane((int)((blockIdx.x * 1024 + t) >> 6));
    const int lane = t & 63;
    if (node >= n) return;
    const float di = dinv[node];
    const int lo = rowptr[node], hi = rowptr[node + 1];
    const ushort_t* __restrict__ hl = h + lane;
    float accE = 0.f;
    int i = lo;
    const int M = (hi - lo) >> 3;    // full 8-edge batches
    if (M >= 2) {
        int2 ec[8], en[8];
        float vc[8];
#pragma unroll
        for (int k = 0; k < 8; ++k) ec[k] = ep[i + k];
#pragma unroll
        for (int k = 0; k < 8; ++k) en[k] = ep[i + 8 + k];
#pragma unroll
        for (int k = 0; k < 8; ++k) vc[k] = bf2f(hl[(size_t)ec[k].x * 64]);
        i += 16;
        for (int m = 0; m < M - 2; ++m, i += 8) {
            float vn[8];
#pragma unroll
            for (int k = 0; k < 8; ++k) vn[k] = bf2f(hl[(size_t)en[k].x * 64]);
            int2 e2[8];
#pragma unroll
            for (int k = 0; k < 8; ++k) e2[k] = ep[i + k];
#pragma unroll
            for (int k = 0; k < 8; ++k) accE = fmaf(vc[k], __int_as_float(ec[k].y), accE);
#pragma unroll
            for (int k = 0; k < 8; ++k) { ec[k] = en[k]; en[k] = e2[k]; vc[k] = vn[k]; }
        }
        // drain: vc in flight for batch M-2 (ep=ec); en = ep of batch M-1
        float vl[8];
#pragma unroll
        for (int k = 0; k < 8; ++k) vl[k] = bf2f(hl[(size_t)en[k].x * 64]);
#pragma unroll
        for (int k = 0; k < 8; ++k) accE = fmaf(vc[k], __int_as_float(ec[k].y), accE);
#pragma unroll
        for (int k = 0; k < 8; ++k) accE = fmaf(vl[k], __int_as_float(en[k].y), accE);
    } else if (M == 1) {
        int2 e[8];
        float v[8];
#pragma unroll
        for (int k = 0; k < 8; ++k) e[k] = ep[i + k];
#pragma unroll
        for (int k = 0; k < 8; ++k) v[k] = bf2f(hl[(size_t)e[k].x * 64]);
#pragma unroll
        for (int k = 0; k < 8; ++k) accE = fmaf(v[k], __int_as_float(e[k].y), accE);
        i += 8;
    }
    for (; i < hi; ++i) {
        int2 p = ep[i];
        accE = fmaf(bf2f(hl[(size_t)p.x * 64]), __int_as_float(p.y), accE);
    }
    float self = bf2f(hl[(size_t)node * 64]);
    float r = di * (accE + self);              // agg1 value for feature `lane`
    // ---- fused gemm2 epilogue: LDS transpose + 4-way split FMA chain ----
    float av = fmaxf(r + b1[lane], 0.0f);
    const int w = t >> 6;                      // wave id in block
    avs[w][lane] = av;
    asm volatile("" ::: "memory");             // keep write before reads
    const int f = lane & 15;
    const int q = lane >> 4;                   // this lane's k-quarter
    const float* ar = &avs[w][q * 16];         // 16 lanes same addr -> broadcast
    float4 a0 = *(const float4*)(ar + 0);
    float4 a1 = *(const float4*)(ar + 4);
    float4 a2 = *(const float4*)(ar + 8);
    float4 a3 = *(const float4*)(ar + 12);
    const float* wr = &W2s[(q * 16) * 17 + f]; // + kk*17 immediate offsets
    float pa = 0.f, pb = 0.f, pc = 0.f, pd = 0.f;
    pa = fmaf(a0.x, wr[0 * 17], pa);
    pa = fmaf(a0.y, wr[1 * 17], pa);
    pa = fmaf(a0.z, wr[2 * 17], pa);
    pa = fmaf(a0.w, wr[3 * 17], pa);
    pb = fmaf(a1.x, wr[4 * 17], pb);
    pb = fmaf(a1.y, wr[5 * 17], pb);
    pb = fmaf(a1.z, wr[6 * 17], pb);
    pb = fmaf(a1.w, wr[7 * 17], pb);
    pc = fmaf(a2.x, wr[8 * 17], pc);
    pc = fmaf(a2.y, wr[9 * 17], pc);
    pc = fmaf(a2.z, wr[10 * 17], pc);
    pc = fmaf(a2.w, wr[11 * 17], pc);
    pd = fmaf(a3.x, wr[12 * 17], pd);
    pd = fmaf(a3.y, wr[13 * 17], pd);
    pd = fmaf(a3.z, wr[14 * 17], pd);
    pd = fmaf(a3.w, wr[15 * 17], pd);
    float p = (pa + pb) + (pc + pd);
    p += __shfl_xor(p, 16, 64);
    p += __shfl_xor(p, 32, 64);
    if (lane < 16) h2[(size_t)node * 16 + f] = f2bf(p * di);
}

// Gather-aggregate F=16 + FUSED log_softmax. R23: one WAVE per node.
// lane = (edge-slot es = lane>>4, feature f = lane&15): one gather covers
// 4 edges; ep batches via s_load (node is readfirstlane'd). Slot partials
// combined by shfl_xor(16/32); self + b2 + group softmax; lane<16 stores.
__global__ __launch_bounds__(256) void k_agg16w(const ushort_t* __restrict__ h,
                                                const int* __restrict__ rowptr,
                                                const int2* __restrict__ ep,
                                                const float* __restrict__ dinv,
                                                const float* __restrict__ b2,
                                                float* __restrict__ out, int n) {
    const int node = __builtin_amdgcn_readfirstlane(
        (int)((blockIdx.x * 256 + threadIdx.x) >> 6));
    const int lane = threadIdx.x & 63;
    if (node >= n) return;
    const int f = lane & 15;         // feature
    const int es = lane >> 4;        // edge slot 0..3
    const float di = dinv[node];
    const int lo = rowptr[node], hi = rowptr[node + 1];
    float acc = 0.f;
    int i = lo;
    if (i + 4 <= hi) {
        int2 pb[4], nb[4];
#pragma unroll
        for (int k = 0; k < 4; ++k) pb[k] = ep[i + k];
        i += 4;
        for (; i + 4 <= hi; i += 4) {
#pragma unroll
            for (int k = 0; k < 4; ++k) nb[k] = ep[i + k];   // prefetch (s_load)
            int sv = pb[0].x, wv = pb[0].y;
            sv = (es == 1) ? pb[1].x : sv;  wv = (es == 1) ? pb[1].y : wv;
            sv = (es == 2) ? pb[2].x : sv;  wv = (es == 2) ? pb[2].y : wv;
            sv = (es == 3) ? pb[3].x : sv;  wv = (es == 3) ? pb[3].y : wv;
            float v = bf2f(h[(size_t)sv * 16 + f]);
            acc = fmaf(v, __int_as_float(wv), acc);
#pragma unroll
            for (int k = 0; k < 4; ++k) pb[k] = nb[k];
        }
        {   // drain last full batch
            int sv = pb[0].x, wv = pb[0].y;
            sv = (es == 1) ? pb[1].x : sv;  wv = (es == 1) ? pb[1].y : wv;
            sv = (es == 2) ? pb[2].x : sv;  wv = (es == 2) ? pb[2].y : wv;
            sv = (es == 3) ? pb[3].x : sv;  wv = (es == 3) ? pb[3].y : wv;
            float v = bf2f(h[(size_t)sv * 16 + f]);
            acc = fmaf(v, __int_as_float(wv), acc);
        }
    }
    if (i < hi) {                    // tail: <4 edges, mask by slot
        int rem = hi - i;            // 1..3
        int2 p = ep[i + ((es < rem) ? es : 0)];
        float v = bf2f(h[(size_t)p.x * 16 + f]);
        float w = (es < rem) ? __int_as_float(p.y) : 0.0f;
        acc = fmaf(v, w, acc);
    }
    // combine the 4 edge-slot partials (all lanes end with the full sum)
    acc += __shfl_xor(acc, 16, 64);
    acc += __shfl_xor(acc, 32, 64);
    float self = bf2f(h[(size_t)node * 16 + f]);
    float v = di * (acc + self) + b2[f];
    // ---- fused log_softmax over the 16 features (any 16-lane group) ----
    float m = v;
    m = fmaxf(m, __shfl_xor(m, 1, 64));
    m = fmaxf(m, __shfl_xor(m, 2, 64));
    m = fmaxf(m, __shfl_xor(m, 4, 64));
    m = fmaxf(m, __shfl_xor(m, 8, 64));
    float e = __expf(v - m);
    float s = e;
    s += __shfl_xor(s, 1, 64);
    s += __shfl_xor(s, 2, 64);
    s += __shfl_xor(s, 4, 64);
    s += __shfl_xor(s, 8, 64);
    if (lane < 16) out[(size_t)node * 16 + f] = v - m - __logf(s);
}

extern "C" void kernel_launch(void* const* d_in, const int* in_sizes, int n_in,
                              void* d_out, int out_size, void* d_ws, size_t ws_size,
                              hipStream_t stream) {
    const float* x  = (const float*)d_in[0];
    const int*   ei = (const int*)d_in[1];   // [2, E]
    const float* ew = (const float*)d_in[2];
    const float* W1 = (const float*)d_in[3];
    const float* b1 = (const float*)d_in[4];
    const float* W2 = (const float*)d_in[5];
    const float* b2 = (const float*)d_in[6];
    float* out = (float*)d_out;

    const int n = in_sizes[0] / 128;  // 100000
    const int E = in_sizes[2];        // 1600000
    const int* srcv = ei;
    const int* dstv = ei + E;
    const int nbuk = (n + BNODES - 1) >> BSHIFT;  // 782

    // Workspace (4B units). tmp (19.2MB) aliases agg1 region (dead after p2);
    // h2 (bf16[n*16], 3.2MB) also lands there (h1b is still read by agg64f).
    float* wsf = (float*)d_ws;
    size_t off = 0;
    float* dinv = wsf + off; off += n;
    ushort_t* h1b = (ushort_t*)(wsf + off); off += (size_t)n * 32;  // bf16[n*64]
    float* agg1 = wsf + off; off += (size_t)n * 64;                 // tmp/h2 arena
    off = (off + 1) & ~(size_t)1;                     // 8B align
    int2* epack = (int2*)(wsf + off); off += (size_t)E * 2;
    int* rowptr = (int*)(wsf + off); off += n + 1;
    int* boff_d = (int*)(wsf + off); off += NBUK_MAX + 1;
    int* bcur   = (int*)(wsf + off); off += (size_t)NBUK_MAX * CSTR;
    int2* tmp   = (int2*)agg1;                        // [nbuk*CAP]
    ushort_t* h2b = (ushort_t*)agg1;                  // bf16[n*16], after tmp dies

    const int TB = 256;

    // --- CSR build: cursor init -> block-aggregated append -> scan -> finalize ---
    k_binit<<<1, 1024, 0, stream>>>(bcur, nbuk);
    k_p1<<<(E + CHUNK - 1) / CHUNK, P1_TB, 0, stream>>>(srcv, dstv, ew, bcur, tmp, E, nbuk);
    k_pscan<<<1, 1024, 0, stream>>>(bcur, boff_d, nbuk);
    k_p2<<<nbuk, TB, 0, stream>>>(tmp, bcur, boff_d, rowptr, epack, dinv, n, nbuk);

    // --- layer 1: gemm (dinv-prescaled, bf16 out) + gather-agg w/ fused gemm2 ---
    k_gemm1<<<(n + 63) / 64, TB, 0, stream>>>(x, W1, dinv, h1b, n);
    k_agg64f<<<(n * 64 + 1023) / 1024, 1024, 0, stream>>>(h1b, rowptr, epack, dinv,
                                                          W2, b1, h2b, n);

    // --- layer 2 gather-agg (wave/node, 4-edge gathers) w/ fused log_softmax ---
    k_agg16w<<<(n * 64 + TB - 1) / TB, TB, 0, stream>>>(h2b, rowptr, epack, dinv,
                                                        b2, out, n);
}

// Round 13
// 266.855 us; speedup vs baseline: 1.0551x; 1.0551x over previous
//
#include <hip/hip_runtime.h>

// ---------------------------------------------------------------------------
// GCN 2-layer, CSR-gather. R24 (on R23 = 281.5us regression):
//  - R23 post-mortem: agg16w (wave/node) cost +12us vs R20's agg16f (lost
//    4 independent gather streams/wave + cndmask overhead). REVERTED.
//  - k_p2 v2: LDS-staged scatter. Old form scattered 8B epack entries at
//    random positions in each bucket's 16KB window (~2-entry runs -> ~4x
//    write amp, the R17 p1 pathology). Now: stage tmp segment in LDS (24KB),
//    histogram same pass, scatter in LDS, write epack linearly coalesced.
//    Edge order within node changes (fp32 reorder noise << bf16 quant).
//  - agg64f/gemm1/p1/pscan unchanged (R22 measured forms).
// ---------------------------------------------------------------------------

#define BSHIFT 7
#define BNODES 128
#define NBUK_MAX 1024
#define CSTR 16
#define CAP 3072
#define CHUNK 8192
#define EPB 8
#define P1_TB 1024

typedef unsigned short ushort_t;
typedef unsigned int uint_t;
typedef unsigned short us4 __attribute__((ext_vector_type(4)));

__device__ inline ushort_t f2bf(float f) {   // round-to-nearest-even
    uint_t u = __float_as_uint(f);
    return (ushort_t)((u + 0x7FFF + ((u >> 16) & 1)) >> 16);
}
__device__ inline float bf2f(ushort_t b) {
    return __uint_as_float(((uint_t)b) << 16);
}

// init strided cursors to their segment bases
__global__ __launch_bounds__(1024) void k_binit(int* __restrict__ bcur, int nbuk) {
    int t = threadIdx.x;
    if (t < nbuk) bcur[t * CSTR] = t * CAP;
}

// Pass 1: block-aggregated bucket append (R18: 1024 threads, CHUNK 8192).
__global__ __launch_bounds__(1024) void k_p1(const int* __restrict__ src,
                                             const int* __restrict__ dst,
                                             const float* __restrict__ ew,
                                             int* __restrict__ bcur,
                                             int2* __restrict__ tmp, int E, int nbuk) {
    __shared__ int lcnt[NBUK_MAX];
    __shared__ int lbase[NBUK_MAX];
    const int t = threadIdx.x;
    const int base = blockIdx.x * CHUNK;
    for (int j = t; j < nbuk; j += P1_TB) lcnt[j] = 0;
    __syncthreads();
    int d_r[EPB];
#pragma unroll
    for (int k = 0; k < EPB; ++k) {
        int e = base + k * P1_TB + t;
        int d = (e < E) ? dst[e] : -1;
        d_r[k] = d;
        if (d >= 0) atomicAdd(&lcnt[d >> BSHIFT], 1);
    }
    __syncthreads();
    for (int j = t; j < nbuk; j += P1_TB) {
        int c = lcnt[j];
        lbase[j] = c ? atomicAdd(&bcur[j * CSTR], c) : 0;
        lcnt[j] = 0;
    }
    __syncthreads();
#pragma unroll
    for (int k = 0; k < EPB; ++k) {
        int d = d_r[k];
        if (d < 0) continue;
        int e = base + k * P1_TB + t;
        int b = d >> BSHIFT;
        int p = lbase[b] + atomicAdd(&lcnt[b], 1);
        if (p >= nbuk * CAP) continue;
        int2 pk;
        pk.x = src[e] | ((d & (BNODES - 1)) << 17);
        pk.y = __float_as_int(ew[e]);
        tmp[p] = pk;
    }
}

// Scan final bucket counts -> dense boff[nbuk+1].
__global__ __launch_bounds__(1024) void k_pscan(const int* __restrict__ bcur,
                                                int* __restrict__ boff, int nbuk) {
    __shared__ int lds[1024];
    const int t = threadIdx.x;
    int v = (t < nbuk) ? (bcur[t * CSTR] - t * CAP) : 0;
    lds[t] = v;
    __syncthreads();
    for (int off = 1; off < 1024; off <<= 1) {
        int u = (t >= off) ? lds[t - off] : 0;
        __syncthreads();
        lds[t] += u;
        __syncthreads();
    }
    if (t < nbuk) boff[t] = lds[t] - v;
    if (t == nbuk - 1) boff[nbuk] = lds[t];
}

// Pass 2 v2: per-bucket finalize with LDS staging -> dense CSR epack,
// rowptr, dinv. Scatter happens in LDS; epack written linearly coalesced.
__global__ __launch_bounds__(256) void k_p2(const int2* __restrict__ tmp,
                                            const int* __restrict__ bcur,
                                            const int* __restrict__ boff,
                                            int* __restrict__ rowptr,
                                            int2* __restrict__ epack,
                                            float* __restrict__ dinv,
                                            int n, int nbuk) {
    __shared__ int cnt[BNODES];
    __shared__ int pos[BNODES];
    __shared__ float degf[BNODES];
    __shared__ int2 buf[CAP];        // 24 KB staged bucket segment
    __shared__ int2 sbuf[CAP];       // 24 KB scatter target
    const int b = blockIdx.x, t = threadIdx.x;
    const int node0 = b << BSHIFT;
    if (t < BNODES) { cnt[t] = 0; degf[t] = 0.f; }
    __syncthreads();
    const int lo_t = b * CAP;
    int cntT = bcur[b * CSTR] - lo_t;
    if (cntT > CAP) cntT = CAP;      // LDS safety (stat. never hit)
    const int outb = boff[b];
    for (int i = t; i < cntT; i += 256) {
        int2 pk = tmp[lo_t + i];
        buf[i] = pk;
        int dlo = (pk.x >> 17) & (BNODES - 1);
        atomicAdd(&cnt[dlo], 1);
        atomicAdd(&degf[dlo], __int_as_float(pk.y));
    }
    __syncthreads();
    int own = (t < BNODES) ? cnt[t] : 0;
    if (t < BNODES) pos[t] = own;
    __syncthreads();
    for (int off = 1; off < BNODES; off <<= 1) {
        int u = (t < BNODES && t >= off) ? pos[t - off] : 0;
        __syncthreads();
        if (t < BNODES) pos[t] += u;
        __syncthreads();
    }
    if (t < BNODES) {
        int excl = pos[t] - own;
        int node = node0 + t;
        if (node < n) {
            rowptr[node] = outb + excl;
            dinv[node] = rsqrtf(1.0f + degf[t]);
        }
        pos[t] = excl;
    }
    if (b == nbuk - 1 && t == 0) rowptr[n] = outb + cntT;
    __syncthreads();
    // scatter within LDS (block-local positions)
    for (int i = t; i < cntT; i += 256) {
        int2 pk = buf[i];
        int dlo = (pk.x >> 17) & (BNODES - 1);
        int p = atomicAdd(&pos[dlo], 1);
        int2 o;
        o.x = pk.x & 0x1FFFF;
        o.y = pk.y;
        sbuf[p] = o;
    }
    __syncthreads();
    // linear coalesced write-out
    for (int i = t; i < cntT; i += 256) epack[outb + i] = sbuf[i];
}

// h1s[n][64] (bf16) = (x[n][128] @ W[128][64]) * dinv[node]
// 64-node block; thread = (ng, fg) owns nodes {ng+16j} x feats {4fg..4fg+3}.
// K in FOUR 32-quarters; Ws 8KB + xs[64][36] 9KB = 17KB -> 8 blocks/CU.
__global__ __launch_bounds__(256) void k_gemm1(const float* __restrict__ x,
                                               const float* __restrict__ W,
                                               const float* __restrict__ dinv,
                                               ushort_t* __restrict__ h, int n) {
    __shared__ float Ws[32 * 64];    // 8 KB  current quarter's [kk][f]
    __shared__ float xs[64][36];     // 9 KB  quarter-K tile, +4 pad
    const int t = threadIdx.x;
    const int node0 = blockIdx.x * 64;
    const int fg = t & 15;           // feature quad: f = 4fg..4fg+3
    const int ng = t >> 4;           // 0..15; this thread's nodes: ng + 16j
    float4 acc[4];
#pragma unroll
    for (int j = 0; j < 4; ++j) acc[j] = make_float4(0.f, 0.f, 0.f, 0.f);
    const float4* Ws4 = (const float4*)Ws;   // Ws4[kk*16 + fg]
    for (int quar = 0; quar < 4; ++quar) {
        __syncthreads();             // LDS reuse guard
        for (int i = t; i < 32 * 64; i += 256) Ws[i] = W[quar * 2048 + i];
        for (int i = t; i < 64 * 8; i += 256) {
            int nn = i >> 3, q = i & 7;
            int node = node0 + nn;
            float4 v = (node < n) ? ((const float4*)x)[(size_t)node * 32 + quar * 8 + q]
                                  : make_float4(0.f, 0.f, 0.f, 0.f);
            *(float4*)&xs[nn][q * 4] = v;
        }
        __syncthreads();
#pragma unroll
        for (int kb = 0; kb < 8; ++kb) {
            float4 xv[4];
#pragma unroll
            for (int j = 0; j < 4; ++j)
                xv[j] = *(const float4*)&xs[ng + 16 * j][kb * 4];
            float4 w0 = Ws4[(kb * 4 + 0) * 16 + fg];
            float4 w1 = Ws4[(kb * 4 + 1) * 16 + fg];
            float4 w2 = Ws4[(kb * 4 + 2) * 16 + fg];
            float4 w3 = Ws4[(kb * 4 + 3) * 16 + fg];
#pragma unroll
            for (int j = 0; j < 4; ++j) {
                acc[j].x = fmaf(xv[j].x, w0.x, acc[j].x);
                acc[j].y = fmaf(xv[j].x, w0.y, acc[j].y);
                acc[j].z = fmaf(xv[j].x, w0.z, acc[j].z);
                acc[j].w = fmaf(xv[j].x, w0.w, acc[j].w);
                acc[j].x = fmaf(xv[j].y, w1.x, acc[j].x);
                acc[j].y = fmaf(xv[j].y, w1.y, acc[j].y);
                acc[j].z = fmaf(xv[j].y, w1.z, acc[j].z);
                acc[j].w = fmaf(xv[j].y, w1.w, acc[j].w);
                acc[j].x = fmaf(xv[j].z, w2.x, acc[j].x);
                acc[j].y = fmaf(xv[j].z, w2.y, acc[j].y);
                acc[j].z = fmaf(xv[j].z, w2.z, acc[j].z);
                acc[j].w = fmaf(xv[j].z, w2.w, acc[j].w);
                acc[j].x = fmaf(xv[j].w, w3.x, acc[j].x);
                acc[j].y = fmaf(xv[j].w, w3.y, acc[j].y);
                acc[j].z = fmaf(xv[j].w, w3.z, acc[j].z);
                acc[j].w = fmaf(xv[j].w, w3.w, acc[j].w);
            }
        }
    }
#pragma unroll
    for (int j = 0; j < 4; ++j) {
        int node = node0 + ng + 16 * j;
        if (node < n) {
            float di = dinv[node];
            us4 pk;
            pk.x = f2bf(acc[j].x * di);
            pk.y = f2bf(acc[j].y * di);
            pk.z = f2bf(acc[j].z * di);
            pk.w = f2bf(acc[j].w * di);
            *(us4*)(h + (size_t)node * 64 + fg * 4) = pk;   // one 8B store
        }
    }
}

// Gather-aggregate F=64 with FUSED layer-2 gemm. One wave per node, lane =
// feature. R22 form: 1024-thread blocks, 2-deep pipeline, LDS epilogue.
__global__ __launch_bounds__(1024) void k_agg64f(const ushort_t* __restrict__ h,
                                                 const int* __restrict__ rowptr,
                                                 const int2* __restrict__ ep,
                                                 const float* __restrict__ dinv,
                                                 const float* __restrict__ W2,
                                                 const float* __restrict__ b1,
                                                 ushort_t* __restrict__ h2, int n) {
    __shared__ float W2s[64 * 17];   // padded [k][f]: W2s[k*17+f], 4.25 KB
    __shared__ float avs[16][64];    // per-wave relu'd agg row, 4 KB
    const int t = threadIdx.x;
    if (t < 64 * 16) {
        int k = t >> 4, f = t & 15;
        W2s[k * 17 + f] = W2[t];
    }
    __syncthreads();                 // before any divergent return
    const int node = __builtin_amdgcn_readfirstlane((int)((blockIdx.x * 1024 + t) >> 6));
    const int lane = t & 63;
    if (node >= n) return;
    const float di = dinv[node];
    const int lo = rowptr[node], hi = rowptr[node + 1];
    const ushort_t* __restrict__ hl = h + lane;
    float accE = 0.f;
    int i = lo;
    const int M = (hi - lo) >> 3;    // full 8-edge batches
    if (M >= 2) {
        int2 ec[8], en[8];
        float vc[8];
#pragma unroll
        for (int k = 0; k < 8; ++k) ec[k] = ep[i + k];
#pragma unroll
        for (int k = 0; k < 8; ++k) en[k] = ep[i + 8 + k];
#pragma unroll
        for (int k = 0; k < 8; ++k) vc[k] = bf2f(hl[(size_t)ec[k].x * 64]);
        i += 16;
        for (int m = 0; m < M - 2; ++m, i += 8) {
            float vn[8];
#pragma unroll
            for (int k = 0; k < 8; ++k) vn[k] = bf2f(hl[(size_t)en[k].x * 64]);
            int2 e2[8];
#pragma unroll
            for (int k = 0; k < 8; ++k) e2[k] = ep[i + k];
#pragma unroll
            for (int k = 0; k < 8; ++k) accE = fmaf(vc[k], __int_as_float(ec[k].y), accE);
#pragma unroll
            for (int k = 0; k < 8; ++k) { ec[k] = en[k]; en[k] = e2[k]; vc[k] = vn[k]; }
        }
        // drain: vc in flight for batch M-2 (ep=ec); en = ep of batch M-1
        float vl[8];
#pragma unroll
        for (int k = 0; k < 8; ++k) vl[k] = bf2f(hl[(size_t)en[k].x * 64]);
#pragma unroll
        for (int k = 0; k < 8; ++k) accE = fmaf(vc[k], __int_as_float(ec[k].y), accE);
#pragma unroll
        for (int k = 0; k < 8; ++k) accE = fmaf(vl[k], __int_as_float(en[k].y), accE);
    } else if (M == 1) {
        int2 e[8];
        float v[8];
#pragma unroll
        for (int k = 0; k < 8; ++k) e[k] = ep[i + k];
#pragma unroll
        for (int k = 0; k < 8; ++k) v[k] = bf2f(hl[(size_t)e[k].x * 64]);
#pragma unroll
        for (int k = 0; k < 8; ++k) accE = fmaf(v[k], __int_as_float(e[k].y), accE);
        i += 8;
    }
    for (; i < hi; ++i) {
        int2 p = ep[i];
        accE = fmaf(bf2f(hl[(size_t)p.x * 64]), __int_as_float(p.y), accE);
    }
    float self = bf2f(hl[(size_t)node * 64]);
    float r = di * (accE + self);              // agg1 value for feature `lane`
    // ---- fused gemm2 epilogue: LDS transpose + 4-way split FMA chain ----
    float av = fmaxf(r + b1[lane], 0.0f);
    const int w = t >> 6;                      // wave id in block
    avs[w][lane] = av;
    asm volatile("" ::: "memory");             // keep write before reads
    const int f = lane & 15;
    const int q = lane >> 4;                   // this lane's k-quarter
    const float* ar = &avs[w][q * 16];         // 16 lanes same addr -> broadcast
    float4 a0 = *(const float4*)(ar + 0);
    float4 a1 = *(const float4*)(ar + 4);
    float4 a2 = *(const float4*)(ar + 8);
    float4 a3 = *(const float4*)(ar + 12);
    const float* wr = &W2s[(q * 16) * 17 + f]; // + kk*17 immediate offsets
    float pa = 0.f, pb = 0.f, pc = 0.f, pd = 0.f;
    pa = fmaf(a0.x, wr[0 * 17], pa);
    pa = fmaf(a0.y, wr[1 * 17], pa);
    pa = fmaf(a0.z, wr[2 * 17], pa);
    pa = fmaf(a0.w, wr[3 * 17], pa);
    pb = fmaf(a1.x, wr[4 * 17], pb);
    pb = fmaf(a1.y, wr[5 * 17], pb);
    pb = fmaf(a1.z, wr[6 * 17], pb);
    pb = fmaf(a1.w, wr[7 * 17], pb);
    pc = fmaf(a2.x, wr[8 * 17], pc);
    pc = fmaf(a2.y, wr[9 * 17], pc);
    pc = fmaf(a2.z, wr[10 * 17], pc);
    pc = fmaf(a2.w, wr[11 * 17], pc);
    pd = fmaf(a3.x, wr[12 * 17], pd);
    pd = fmaf(a3.y, wr[13 * 17], pd);
    pd = fmaf(a3.z, wr[14 * 17], pd);
    pd = fmaf(a3.w, wr[15 * 17], pd);
    float p = (pa + pb) + (pc + pd);
    p += __shfl_xor(p, 16, 64);
    p += __shfl_xor(p, 32, 64);
    if (lane < 16) h2[(size_t)node * 16 + f] = f2bf(p * di);
}

// Gather-aggregate F=16 with FUSED log_softmax(+b2). 16-lane group per node,
// 4 rows in flight (R20 measured form — R21/R23 rewrites both regressed).
__global__ __launch_bounds__(256) void k_agg16f(const ushort_t* __restrict__ h,
                                                const int* __restrict__ rowptr,
                                                const int2* __restrict__ ep,
                                                const float* __restrict__ dinv,
                                                const float* __restrict__ b2,
                                                float* __restrict__ out, int n) {
    const int node = (blockIdx.x * 256 + threadIdx.x) >> 4;
    const int lane = threadIdx.x & 15;
    if (node >= n) return;
    const float di = dinv[node];
    float accE = 0.f;
    const int lo = rowptr[node], hi = rowptr[node + 1];
    int i = lo;
    for (; i + 3 < hi; i += 4) {
        int2 p0 = ep[i], p1 = ep[i + 1], p2 = ep[i + 2], p3 = ep[i + 3];
        float v0 = bf2f(h[(size_t)p0.x * 16 + lane]);
        float v1 = bf2f(h[(size_t)p1.x * 16 + lane]);
        float v2 = bf2f(h[(size_t)p2.x * 16 + lane]);
        float v3 = bf2f(h[(size_t)p3.x * 16 + lane]);
        accE = fmaf(v0, __int_as_float(p0.y), accE);
        accE = fmaf(v1, __int_as_float(p1.y), accE);
        accE = fmaf(v2, __int_as_float(p2.y), accE);
        accE = fmaf(v3, __int_as_float(p3.y), accE);
    }
    for (; i < hi; ++i) {
        int2 p = ep[i];
        accE = fmaf(bf2f(h[(size_t)p.x * 16 + lane]), __int_as_float(p.y), accE);
    }
    float self = bf2f(h[(size_t)node * 16 + lane]);
    float v = di * (accE + self) + b2[lane];
    // ---- fused log_softmax over the 16-lane group ----
    float m = v;
    m = fmaxf(m, __shfl_xor(m, 1, 64));
    m = fmaxf(m, __shfl_xor(m, 2, 64));
    m = fmaxf(m, __shfl_xor(m, 4, 64));
    m = fmaxf(m, __shfl_xor(m, 8, 64));
    float e = __expf(v - m);
    float s = e;
    s += __shfl_xor(s, 1, 64);
    s += __shfl_xor(s, 2, 64);
    s += __shfl_xor(s, 4, 64);
    s += __shfl_xor(s, 8, 64);
    out[(size_t)node * 16 + lane] = v - m - __logf(s);
}

extern "C" void kernel_launch(void* const* d_in, const int* in_sizes, int n_in,
                              void* d_out, int out_size, void* d_ws, size_t ws_size,
                              hipStream_t stream) {
    const float* x  = (const float*)d_in[0];
    const int*   ei = (const int*)d_in[1];   // [2, E]
    const float* ew = (const float*)d_in[2];
    const float* W1 = (const float*)d_in[3];
    const float* b1 = (const float*)d_in[4];
    const float* W2 = (const float*)d_in[5];
    const float* b2 = (const float*)d_in[6];
    float* out = (float*)d_out;

    const int n = in_sizes[0] / 128;  // 100000
    const int E = in_sizes[2];        // 1600000
    const int* srcv = ei;
    const int* dstv = ei + E;
    const int nbuk = (n + BNODES - 1) >> BSHIFT;  // 782

    // Workspace (4B units). tmp (19.2MB) aliases agg1 region (dead after p2);
    // h2 (bf16[n*16], 3.2MB) also lands there (h1b is still read by agg64f).
    float* wsf = (float*)d_ws;
    size_t off = 0;
    float* dinv = wsf + off; off += n;
    ushort_t* h1b = (ushort_t*)(wsf + off); off += (size_t)n * 32;  // bf16[n*64]
    float* agg1 = wsf + off; off += (size_t)n * 64;                 // tmp/h2 arena
    off = (off + 1) & ~(size_t)1;                     // 8B align
    int2* epack = (int2*)(wsf + off); off += (size_t)E * 2;
    int* rowptr = (int*)(wsf + off); off += n + 1;
    int* boff_d = (int*)(wsf + off); off += NBUK_MAX + 1;
    int* bcur   = (int*)(wsf + off); off += (size_t)NBUK_MAX * CSTR;
    int2* tmp   = (int2*)agg1;                        // [nbuk*CAP]
    ushort_t* h2b = (ushort_t*)agg1;                  // bf16[n*16], after tmp dies

    const int TB = 256;

    // --- CSR build: cursor init -> block-aggregated append -> scan -> finalize ---
    k_binit<<<1, 1024, 0, stream>>>(bcur, nbuk);
    k_p1<<<(E + CHUNK - 1) / CHUNK, P1_TB, 0, stream>>>(srcv, dstv, ew, bcur, tmp, E, nbuk);
    k_pscan<<<1, 1024, 0, stream>>>(bcur, boff_d, nbuk);
    k_p2<<<nbuk, TB, 0, stream>>>(tmp, bcur, boff_d, rowptr, epack, dinv, n, nbuk);

    // --- layer 1: gemm (dinv-prescaled, bf16 out) + gather-agg w/ fused gemm2 ---
    k_gemm1<<<(n + 63) / 64, TB, 0, stream>>>(x, W1, dinv, h1b, n);
    k_agg64f<<<(n * 64 + 1023) / 1024, 1024, 0, stream>>>(h1b, rowptr, epack, dinv,
                                                          W2, b1, h2b, n);

    // --- layer 2 gather-agg w/ fused +b2 + log_softmax -> d_out ---
    k_agg16f<<<(n * 16 + TB - 1) / TB, TB, 0, stream>>>(h2b, rowptr, epack, dinv,
                                                        b2, out, n);
}